// Round 1
// baseline (1154.849 us; speedup 1.0000x reference)
//
#include <hip/hip_runtime.h>
#include <stdint.h>

// Problem constants
#define B_   4
#define NQ_  2048
#define SK_  2048
#define H_   16
#define HS_  1024   // HSIZE = OSIZE = ISIZE
#define D_   64

typedef __attribute__((ext_vector_type(8))) short bf16x8;          // MFMA A/B frag (4 VGPR)
typedef __attribute__((ext_vector_type(4))) float f32x4;           // MFMA C/D frag
typedef __attribute__((ext_vector_type(2))) float f32x2;           // packed-f32 pair
typedef __attribute__((ext_vector_type(8))) unsigned short u16x8;  // 8 bf16 = 16B
typedef __attribute__((ext_vector_type(4))) int i32x4;             // 4 int32 = 16B

#define DEVI __device__ __forceinline__

// fp32 -> bf16, round-half-up (1 v_add)
DEVI unsigned short f2bf_hu(float f) {
  union { float f; unsigned int i; } x; x.f = f;
  return (unsigned short)((x.i + 0x8000u) >> 16);
}
// two fp32 -> packed bf16x2: 2 v_add + 1 v_perm
DEVI unsigned int pack2(float a, float b) {
  union { float f; unsigned int i; } x, y; x.f = a; y.f = b;
  return __builtin_amdgcn_perm(y.i + 0x8000u, x.i + 0x8000u, 0x07060302u);
}
DEVI u16x8 cvt8(f32x4 lo, f32x4 hi) {  // 8 fp32 -> 8 bf16
  union { u16x8 s; unsigned int w[4]; } r;
  r.w[0] = pack2(lo[0], lo[1]);
  r.w[1] = pack2(lo[2], lo[3]);
  r.w[2] = pack2(hi[0], hi[1]);
  r.w[3] = pack2(hi[2], hi[3]);
  return r.s;
}
DEVI void async16(void* lds, const void* g) {  // 16B global->LDS DMA (dest = lane-contiguous)
  __builtin_amdgcn_global_load_lds(
      (const __attribute__((address_space(1))) unsigned int*)g,
      (__attribute__((address_space(3))) unsigned int*)lds, 16, 0, 0);
}

// ---- packed-f32 VOP3P helpers (CDNA has v_pk_{fma,mul,add}_f32) ----
DEVI f32x2 pkfma(f32x2 a, f32x2 b, f32x2 c) {
  f32x2 d;
  asm("v_pk_fma_f32 %0, %1, %2, %3" : "=v"(d) : "v"(a), "v"(b), "v"(c));
  return d;
}
DEVI f32x2 pkmul(f32x2 a, f32x2 b) {
  f32x2 d;
  asm("v_pk_mul_f32 %0, %1, %2" : "=v"(d) : "v"(a), "v"(b));
  return d;
}
DEVI f32x2 pkadd(f32x2 a, f32x2 b) {
  f32x2 d;
  asm("v_pk_add_f32 %0, %1, %2" : "=v"(d) : "v"(a), "v"(b));
  return d;
}
// 2 f32 -> 1 u32 of 2 bf16 (RNE), dst.lo = cvt(lo), dst.hi = cvt(hi)
DEVI unsigned int cvtpk_bf16(float lo, float hi) {
  unsigned int r;
  asm("v_cvt_pk_bf16_f32 %0, %1, %2" : "=v"(r) : "v"(lo), "v"(hi));
  return r;
}

// LDS swizzle for [R][64] bf16 tiles (128B rows): XOR 16B-slot with row&7.
// Keeps 4/8/16B alignment; all staged reads/writes land at the free 2-way
// bank-aliasing minimum (m136).
#define SWZB(row, colb) ((((row) * 128) + (colb)) ^ (((row) & 7) << 4))

// ---------------------------------------------------------------------------
// Prep: fp32 -> bf16 for one activation tensor (naBlocks*2048 elems) and one
// weight tensor (rest of grid). Memory-bound.
// ---------------------------------------------------------------------------
__global__ __launch_bounds__(256)
void cvt_prep(const float* __restrict__ a, unsigned short* __restrict__ ab,
              const float* __restrict__ wsrc, unsigned short* __restrict__ wdst,
              int naBlocks) {
  const int bi = blockIdx.x;
  const float* s; unsigned short* d; size_t base;
  if (bi < naBlocks) { s = a;    d = ab;   base = (size_t)bi * 2048; }
  else               { s = wsrc; d = wdst; base = (size_t)(bi - naBlocks) * 2048; }
  const size_t o = base + (size_t)threadIdx.x * 8;
  f32x4 lo = *(const f32x4*)(s + o);
  f32x4 hi = *(const f32x4*)(s + o + 4);
  *(u16x8*)(d + o) = cvt8(lo, hi);
}

// mask int32 -> bitmask (bit i of word w = mask[w*64+i]); 67 MB -> 2 MB
__global__ __launch_bounds__(256)
void pack_mask(const int* __restrict__ m, unsigned long long* __restrict__ bits) {
  const size_t tid = (size_t)blockIdx.x * 256 + threadIdx.x;
  const unsigned long long bal = __ballot(m[tid] != 0);
  if ((threadIdx.x & 63) == 0) bits[tid >> 6] = bal;
}

// mask int32 -> f32 addend (masked ? -1e9 : bias). Folds SparseNormer bias and
// masking into a single value consumed by one v_pk_fma_f32 in the attn kernel.
__global__ __launch_bounds__(256)
void mask_madd(const int* __restrict__ m, float* __restrict__ madd,
               const float* __restrict__ snb) {
  const float bias = snb[0];
  const size_t i = ((size_t)blockIdx.x * 256 + threadIdx.x) * 4;
  const i32x4 mv = *(const i32x4*)(m + i);
  f32x4 o;
#pragma unroll
  for (int r = 0; r < 4; r++) o[r] = mv[r] ? -1e9f : bias;
  *(f32x4*)(madd + i) = o;
}

// ---------------------------------------------------------------------------
// FAST GEMM: C[M][N] = A[M][K] @ W[N][K]^T, A/W bf16 via global_load_lds(16B).
// 128x128 tile, BK=32, 4 waves. XOR swizzle (colgrp ^ ((row>>1)&3)) applied on
// the GLOBAL side so LDS dest stays lane-contiguous for the DMA while frag
// ds_read_b128 lands exactly 2-way per bank (free, m136).
// ---------------------------------------------------------------------------
template <bool CF32>
__global__ __launch_bounds__(256)
void gemm_bb(const unsigned short* __restrict__ A, const unsigned short* __restrict__ Wb,
             void* __restrict__ Cp, int M, int N, int K) {
  __shared__ unsigned short As[128 * 32];
  __shared__ unsigned short Bs[128 * 32];
  const int t = threadIdx.x;
  const int w = t >> 6, l = t & 63;
  const int lm = l & 15, lg = l >> 4;
  const int bm = blockIdx.x * 128, bn = blockIdx.y * 128;
  const int wm = (w >> 1) * 64, wn = (w & 1) * 64;

  const int sr = t >> 2;                            // staged row 0..63 (and +64)
  const int sg = ((t & 3) ^ ((t >> 3) & 3)) * 8;    // swizzled global col-group
  const unsigned short* Ag0 = A + (size_t)(bm + sr) * K + sg;
  const unsigned short* Ag1 = A + (size_t)(bm + sr + 64) * K + sg;
  const unsigned short* Wg0 = Wb + (size_t)(bn + sr) * K + sg;
  const unsigned short* Wg1 = Wb + (size_t)(bn + sr + 64) * K + sg;
  unsigned short* lA0 = &As[t * 8];
  unsigned short* lA1 = &As[t * 8 + 2048];
  unsigned short* lB0 = &Bs[t * 8];
  unsigned short* lB1 = &Bs[t * 8 + 2048];

  const int fx = (lm >> 1) & 3;  // frag-read swizzle: (row>>1)&3 == (lm>>1)&3
  f32x4 acc[4][4] = {};

  for (int k0 = 0; k0 < K; k0 += 32) {
    async16(lA0, Ag0 + k0);
    async16(lA1, Ag1 + k0);
    async16(lB0, Wg0 + k0);
    async16(lB1, Wg1 + k0);
    __syncthreads();
    bf16x8 aF[4], bF[4];
#pragma unroll
    for (int i = 0; i < 4; i++)
      aF[i] = *(const bf16x8*)&As[(wm + i * 16 + lm) * 32 + ((lg ^ fx) * 8)];
#pragma unroll
    for (int i = 0; i < 4; i++)
      bF[i] = *(const bf16x8*)&Bs[(wn + i * 16 + lm) * 32 + ((lg ^ fx) * 8)];
#pragma unroll
    for (int i = 0; i < 4; i++)
#pragma unroll
      for (int j = 0; j < 4; j++)
        acc[i][j] = __builtin_amdgcn_mfma_f32_16x16x32_bf16(aF[i], bF[j], acc[i][j], 0, 0, 0);
    __syncthreads();
  }
#pragma unroll
  for (int i = 0; i < 4; i++)
#pragma unroll
    for (int j = 0; j < 4; j++) {
      const int row = bm + wm + i * 16 + lg * 4;
      const int col = bn + wn + j * 16 + lm;
#pragma unroll
      for (int r = 0; r < 4; r++) {
        if constexpr (CF32) {
          ((float*)Cp)[(size_t)(row + r) * N + col] = acc[i][j][r];
        } else {
          ((unsigned short*)Cp)[(size_t)(row + r) * N + col] = f2bf_hu(acc[i][j][r]);
        }
      }
    }
}

// ---------------------------------------------------------------------------
// FALLBACK GEMM (round-5): fp32 inputs, cvt-on-stage, register prefetch.
// ---------------------------------------------------------------------------
template <bool ABF16, bool CF32>
__global__ __launch_bounds__(256)
void gemm_bt(const void* __restrict__ Ap, const float* __restrict__ W,
             void* __restrict__ Cp, int M, int N, int K) {
  __shared__ unsigned short As[128 * 40];
  __shared__ unsigned short Bs[128 * 40];
  const int t = threadIdx.x;
  const int w = t >> 6, l = t & 63;
  const int lm = l & 15, lg = l >> 4;
  const int bm = blockIdx.x * 128, bn = blockIdx.y * 128;
  const int wm = (w >> 1) * 64, wn = (w & 1) * 64;
  const int sr = t >> 2, sc = (t & 3) * 8;
  const float* Af = (const float*)Ap;
  const unsigned short* Ab = (const unsigned short*)Ap;
  const size_t ao0 = (size_t)(bm + sr) * K + sc;
  const size_t ao1 = (size_t)(bm + sr + 64) * K + sc;
  const size_t wo0 = (size_t)(bn + sr) * K + sc;
  const size_t wo1 = (size_t)(bn + sr + 64) * K + sc;
  auto loadA = [&](size_t off) -> u16x8 {
    if constexpr (ABF16) {
      return *(const u16x8*)(Ab + off);
    } else {
      f32x4 lo = *(const f32x4*)(Af + off);
      f32x4 hi = *(const f32x4*)(Af + off + 4);
      return cvt8(lo, hi);
    }
  };
  auto loadW = [&](size_t off) -> u16x8 {
    f32x4 lo = *(const f32x4*)(W + off);
    f32x4 hi = *(const f32x4*)(W + off + 4);
    return cvt8(lo, hi);
  };
  u16x8 pa0 = loadA(ao0), pa1 = loadA(ao1);
  u16x8 pb0 = loadW(wo0), pb1 = loadW(wo1);
  f32x4 acc[4][4] = {};
  for (int k0 = 0; k0 < K; k0 += 32) {
    *(u16x8*)&As[sr * 40 + sc]        = pa0;
    *(u16x8*)&As[(sr + 64) * 40 + sc] = pa1;
    *(u16x8*)&Bs[sr * 40 + sc]        = pb0;
    *(u16x8*)&Bs[(sr + 64) * 40 + sc] = pb1;
    __syncthreads();
    if (k0 + 32 < K) {
      pa0 = loadA(ao0 + k0 + 32);
      pa1 = loadA(ao1 + k0 + 32);
      pb0 = loadW(wo0 + k0 + 32);
      pb1 = loadW(wo1 + k0 + 32);
    }
    bf16x8 aF[4], bF[4];
#pragma unroll
    for (int i = 0; i < 4; i++)
      aF[i] = *(const bf16x8*)&As[(wm + i * 16 + lm) * 40 + lg * 8];
#pragma unroll
    for (int i = 0; i < 4; i++)
      bF[i] = *(const bf16x8*)&Bs[(wn + i * 16 + lm) * 40 + lg * 8];
#pragma unroll
    for (int i = 0; i < 4; i++)
#pragma unroll
      for (int j = 0; j < 4; j++)
        acc[i][j] = __builtin_amdgcn_mfma_f32_16x16x32_bf16(aF[i], bF[j], acc[i][j], 0, 0, 0);
    __syncthreads();
  }
#pragma unroll
  for (int i = 0; i < 4; i++)
#pragma unroll
    for (int j = 0; j < 4; j++) {
      const int row = bm + wm + i * 16 + lg * 4;
      const int col = bn + wn + j * 16 + lm;
#pragma unroll
      for (int r = 0; r < 4; r++) {
        if constexpr (CF32) {
          ((float*)Cp)[(size_t)(row + r) * N + col] = acc[i][j][r];
        } else {
          ((unsigned short*)Cp)[(size_t)(row + r) * N + col] = f2bf_hu(acc[i][j][r]);
        }
      }
    }
}

// ---------------------------------------------------------------------------
// SparseNormer attention, one (b, h, 128-q tile) per block, 256 threads.
// MODE 0: int32 mask (fallback)  MODE 1: 2 MB bitmask  MODE 2: f32 addend
// (masked ? -1e9 : bias), consumed by one v_pk_fma_f32 -> 3 VALU/elem softmax.
// All LDS tiles stride-64 with XOR swizzle (SWZB) -> minimal bank aliasing.
// ---------------------------------------------------------------------------
template <int MODE>
__global__ __launch_bounds__(256, 4)
void attn_sn(const unsigned short* __restrict__ Qb,
             const unsigned short* __restrict__ Kb,
             const unsigned short* __restrict__ Vb,
             const int* __restrict__ mask,
             const unsigned int* __restrict__ bits,
             const float* __restrict__ madd,
             const float* __restrict__ snb,
             unsigned short* __restrict__ Ob) {
  __shared__ unsigned short Ks[64 * 64];   // [k][d]      8 KB
  __shared__ unsigned short Vt[64 * 64];   // [d][k]      8 KB
  __shared__ unsigned short Pq[128 * 64];  // [q][k]/[q][d] 16 KB
  // denom buffer overlaid on Ks after the k-loop (Ks dead by then)

  const int h = blockIdx.x, qt = blockIdx.y, b = blockIdx.z;
  const int t = threadIdx.x, w = t >> 6, l = t & 63;
  const int lm = l & 15, lg = l >> 4;
  const int q0 = qt * 128;
  const int wk = (w >> 1) * 32;
  const int wn = (w & 1) * 64;
  const float bias = snb[0];

  char* KsB = (char*)Ks;
  char* VtB = (char*)Vt;
  char* PqB = (char*)Pq;

  bf16x8 bQ[4][2];
#pragma unroll
  for (int ni = 0; ni < 4; ni++)
#pragma unroll
    for (int kf = 0; kf < 2; kf++) {
      const int qq = q0 + wn + ni * 16 + lm;
      bQ[ni][kf] = *(const bf16x8*)&Qb[(size_t)(b * NQ_ + qq) * HS_ + h * D_ + kf * 32 + lg * 8];
    }

  const int kr = t >> 3, kcb = (t & 7) * 16;  // staged K row / col-bytes
  const unsigned short* Kg = Kb + (size_t)(b * SK_) * HS_ + h * D_ + (t & 7) * 8;
  const int va = t & 31;
  const int vc = (t >> 5) * 8;
  const unsigned short* Vg = Vb + (size_t)(b * SK_) * HS_ + h * D_ + vc;
  const int* mbase = mask + (size_t)b * NQ_ * SK_;
  const float* Mg[4];
  if constexpr (MODE == 2) {
#pragma unroll
    for (int ni = 0; ni < 4; ni++)
      Mg[ni] = madd + (size_t)(b * NQ_ + q0 + wn + ni * 16 + lm) * SK_ + wk + lg * 4;
  }

  f32x4 oacc[2][4] = {};
  float dpart[4] = {0.f, 0.f, 0.f, 0.f};
  f32x2 dp2[4] = {};

  u16x8 pk0 = *(const u16x8*)(Kg + (size_t)(kr) * HS_);
  u16x8 pk1 = *(const u16x8*)(Kg + (size_t)(32 + kr) * HS_);
  u16x8 pv0 = *(const u16x8*)(Vg + (size_t)(2 * va) * HS_);
  u16x8 pv1 = *(const u16x8*)(Vg + (size_t)(2 * va + 1) * HS_);

  for (int kt = 0; kt < SK_ / 64; kt++) {
    const int kk0 = kt * 64;
    *(u16x8*)(KsB + SWZB(kr, kcb))      = pk0;
    *(u16x8*)(KsB + SWZB(kr + 32, kcb)) = pk1;
    {
      union { u16x8 s; unsigned int w4[4]; } a0, a1;
      a0.s = pv0; a1.s = pv1;
#pragma unroll
      for (int ww = 0; ww < 4; ww++) {
        unsigned int lo = __builtin_amdgcn_perm(a1.w4[ww], a0.w4[ww], 0x05040100u);
        unsigned int hi = __builtin_amdgcn_perm(a1.w4[ww], a0.w4[ww], 0x07060302u);
        *(unsigned int*)(VtB + SWZB(vc + 2 * ww,     4 * va)) = lo;
        *(unsigned int*)(VtB + SWZB(vc + 2 * ww + 1, 4 * va)) = hi;
      }
    }
    __syncthreads();

    if (kt + 1 < SK_ / 64) {
      const int nk0 = kk0 + 64;
      pk0 = *(const u16x8*)(Kg + (size_t)(nk0 + kr) * HS_);
      pk1 = *(const u16x8*)(Kg + (size_t)(nk0 + 32 + kr) * HS_);
      pv0 = *(const u16x8*)(Vg + (size_t)(nk0 + 2 * va) * HS_);
      pv1 = *(const u16x8*)(Vg + (size_t)(nk0 + 2 * va + 1) * HS_);
    }

    // --- mask / addend preload (hidden under QK^T MFMAs)
    f32x4 ma[4][2];
    i32x4 mq[4][2];
    unsigned int mb[4];
    if constexpr (MODE == 2) {
#pragma unroll
      for (int ni = 0; ni < 4; ni++)
#pragma unroll
        for (int mi = 0; mi < 2; mi++)
          ma[ni][mi] = *(const f32x4*)(Mg[ni] + kk0 + mi * 16);
    } else if constexpr (MODE == 1) {
#pragma unroll
      for (int ni = 0; ni < 4; ni++)
        mb[ni] = bits[(size_t)(b * NQ_ + q0 + wn + ni * 16 + lm) * 64 + kt * 2 + (wk >> 5)];
    } else {
#pragma unroll
      for (int ni = 0; ni < 4; ni++) {
        const int* mrow = mbase + (size_t)(q0 + wn + ni * 16 + lm) * SK_ + kk0 + wk + lg * 4;
#pragma unroll
        for (int mi = 0; mi < 2; mi++) mq[ni][mi] = *(const i32x4*)(mrow + mi * 16);
      }
    }

    // --- S^T = K . Q^T
    bf16x8 aK[2][2];
#pragma unroll
    for (int mi = 0; mi < 2; mi++)
#pragma unroll
      for (int kf = 0; kf < 2; kf++)
        aK[mi][kf] = *(const bf16x8*)(KsB + SWZB(wk + mi * 16 + lm, kf * 64 + lg * 16));
    f32x4 sf[2][4] = {};
    __builtin_amdgcn_s_setprio(1);
#pragma unroll
    for (int mi = 0; mi < 2; mi++)
#pragma unroll
      for (int ni = 0; ni < 4; ni++) {
        sf[mi][ni] = __builtin_amdgcn_mfma_f32_16x16x32_bf16(aK[mi][0], bQ[ni][0], sf[mi][ni], 0, 0, 0);
        sf[mi][ni] = __builtin_amdgcn_mfma_f32_16x16x32_bf16(aK[mi][1], bQ[ni][1], sf[mi][ni], 0, 0, 0);
      }
    __builtin_amdgcn_s_setprio(0);

    // --- mask + relu^2, denom, pack P
    if constexpr (MODE == 2) {
      const f32x2 c8 = {0.125f, 0.125f};
#pragma unroll
      for (int ni = 0; ni < 4; ni++) {
#pragma unroll
        for (int mi = 0; mi < 2; mi++) {
          const f32x4 sv = sf[mi][ni];
          const f32x4 mv = ma[ni][mi];
          f32x2 t01 = pkfma((f32x2){sv[0], sv[1]}, c8, (f32x2){mv[0], mv[1]});
          f32x2 t23 = pkfma((f32x2){sv[2], sv[3]}, c8, (f32x2){mv[2], mv[3]});
          t01[0] = fmaxf(t01[0], 0.f); t01[1] = fmaxf(t01[1], 0.f);
          t23[0] = fmaxf(t23[0], 0.f); t23[1] = fmaxf(t23[1], 0.f);
          const f32x2 u01 = pkmul(t01, t01);
          const f32x2 u23 = pkmul(t23, t23);
          dp2[ni] = pkadd(dp2[ni], u01);
          dp2[ni] = pkadd(dp2[ni], u23);
          const unsigned long long pk =
              (unsigned long long)cvtpk_bf16(u01[0], u01[1]) |
              ((unsigned long long)cvtpk_bf16(u23[0], u23[1]) << 32);
          *(unsigned long long*)(PqB + SWZB(wn + ni * 16 + lm, (wk + mi * 16 + lg * 4) * 2)) = pk;
        }
      }
    } else {
#pragma unroll
      for (int ni = 0; ni < 4; ni++) {
        float dsum = 0.f;
#pragma unroll
        for (int mi = 0; mi < 2; mi++) {
          const f32x4 sv = sf[mi][ni];
          float x2[4];
#pragma unroll
          for (int r = 0; r < 4; r++) {
            float x = fmaxf(sv[r] * 0.125f + bias, 0.f);
            if constexpr (MODE == 1) {
              x = ((mb[ni] >> (mi * 16 + lg * 4 + r)) & 1u) ? 0.f : x;
            } else {
              x = mq[ni][mi][r] ? 0.f : x;
            }
            x2[r] = x * x;
            dsum += x2[r];
          }
          const unsigned long long pk =
              (unsigned long long)pack2(x2[0], x2[1]) |
              ((unsigned long long)pack2(x2[2], x2[3]) << 32);
          *(unsigned long long*)(PqB + SWZB(wn + ni * 16 + lm, (wk + mi * 16 + lg * 4) * 2)) = pk;
        }
        dpart[ni] += dsum;
      }
    }
    __syncthreads();

    // --- O^T += V^T . P^T
#pragma unroll
    for (int k2 = 0; k2 < 2; k2++) {
      bf16x8 aV[2], bP[4];
#pragma unroll
      for (int mi = 0; mi < 2; mi++)
        aV[mi] = *(const bf16x8*)(VtB + SWZB(wk + mi * 16 + lm, k2 * 64 + lg * 16));
#pragma unroll
      for (int ni = 0; ni < 4; ni++)
        bP[ni] = *(const bf16x8*)(PqB + SWZB(wn + ni * 16 + lm, k2 * 64 + lg * 16));
      __builtin_amdgcn_s_setprio(1);
#pragma unroll
      for (int mi = 0; mi < 2; mi++)
#pragma unroll
        for (int ni = 0; ni < 4; ni++)
          oacc[mi][ni] = __builtin_amdgcn_mfma_f32_16x16x32_bf16(aV[mi], bP[ni], oacc[mi][ni], 0, 0, 0);
      __builtin_amdgcn_s_setprio(0);
    }
    __syncthreads();
  }

  float* denomS = (float*)Ks;  // Ks dead; loop-final barrier ordered all reads
#pragma unroll
  for (int ni = 0; ni < 4; ni++) {
    float v = (MODE == 2) ? (dp2[ni][0] + dp2[ni][1]) : dpart[ni];
    v += __shfl_xor(v, 16, 64);
    v += __shfl_xor(v, 32, 64);
    dpart[ni] = v;
  }
  if (((w >> 1) == 0) && (lg == 0)) {
#pragma unroll
    for (int ni = 0; ni < 4; ni++) denomS[wn + ni * 16 + lm] = dpart[ni];
  }
  __syncthreads();
  if (((w >> 1) == 1) && (lg == 0)) {
#pragma unroll
    for (int ni = 0; ni < 4; ni++) denomS[wn + ni * 16 + lm] += dpart[ni];
  }
  __syncthreads();

#pragma unroll
  for (int ni = 0; ni < 4; ni++) {
    const int ql = wn + ni * 16 + lm;
    const float inv = 1.0f / (denomS[ql] + 1e-32f);
#pragma unroll
    for (int mi = 0; mi < 2; mi++) {
      const int d0 = wk + mi * 16 + lg * 4;
      const f32x4 ov = oacc[mi][ni];
      const unsigned long long pk =
          (unsigned long long)cvtpk_bf16(ov[0] * inv, ov[1] * inv) |
          ((unsigned long long)cvtpk_bf16(ov[2] * inv, ov[3] * inv) << 32);
      *(unsigned long long*)(PqB + SWZB(ql, d0 * 2)) = pk;
    }
  }
  __syncthreads();
  const int qf = t >> 1;
  unsigned short* orow = Ob + (size_t)(b * NQ_ + q0 + qf) * HS_ + h * D_ + (t & 1) * 32;
#pragma unroll
  for (int j = 0; j < 4; j++) {
    u16x8 vv = *(const u16x8*)(PqB + SWZB(qf, (t & 1) * 64 + j * 16));
    *(u16x8*)(orow + j * 8) = vv;
  }
}

// ---------------------------------------------------------------------------
extern "C" void kernel_launch(void* const* d_in, const int* in_sizes, int n_in,
                              void* d_out, int out_size, void* d_ws, size_t ws_size,
                              hipStream_t stream) {
  (void)in_sizes; (void)n_in; (void)out_size;
  const float* iQ  = (const float*)d_in[0];
  const float* iK  = (const float*)d_in[1];
  const float* iV  = (const float*)d_in[2];
  const int*   msk = (const int*)d_in[3];
  const float* Wq  = (const float*)d_in[4];
  const float* Wk  = (const float*)d_in[5];
  const float* Wv  = (const float*)d_in[6];
  const float* Wo  = (const float*)d_in[7];
  const float* snb = (const float*)d_in[8];
  float* out = (float*)d_out;

  const size_t TOK = (size_t)B_ * NQ_ * HS_;           // 8.39M elems
  const size_t WE  = (size_t)HS_ * HS_;                // 1.05M elems
  const size_t BITS_B = (size_t)B_ * NQ_ * SK_ / 8;    // 2.10 MB
  const size_t MADD_B = (size_t)B_ * NQ_ * SK_ * 4;    // 67.1 MB
  const size_t NEED1 = (3 * TOK + WE) * 2 + BITS_B;    // 54.5 MB
  const size_t NEED2 = NEED1 + MADD_B;                 // 121.6 MB

  const dim3 gg(64, 8, 1), bb(256, 1, 1);
  const dim3 ga(H_, NQ_ / 128, B_);
  const int M = B_ * NQ_, N = HS_, K = HS_;

  if (ws_size >= NEED1) {
    // --- fast path: bf16 pre-cvt + global_load_lds GEMM + bitmask/addend attn
    unsigned short* Kb = (unsigned short*)d_ws;
    unsigned short* Vb = Kb + TOK;
    unsigned short* Ob = Vb + TOK;
    unsigned short* Wb = Ob + TOK;
    unsigned int* bits = (unsigned int*)(Wb + WE);
    float* madd = (float*)((char*)bits + BITS_B);
    unsigned short* out_us = (unsigned short*)d_out;
    unsigned short* Qb  = out_us;         // d_out lower half (dead before final GEMM)
    unsigned short* INb = out_us + TOK;   // d_out upper half: staging for bf16 A
    const bool useMadd = (ws_size >= NEED2);

    hipLaunchKernelGGL(cvt_prep, dim3(4608), bb, 0, stream, iQ, INb, Wq, Wb, 4096);
    hipLaunchKernelGGL((gemm_bb<false>), gg, bb, 0, stream, INb, Wb, (void*)Qb, M, N, K);
    hipLaunchKernelGGL(cvt_prep, dim3(4608), bb, 0, stream, iK, INb, Wk, Wb, 4096);
    hipLaunchKernelGGL((gemm_bb<false>), gg, bb, 0, stream, INb, Wb, (void*)Kb, M, N, K);
    hipLaunchKernelGGL(cvt_prep, dim3(4608), bb, 0, stream, iV, INb, Wv, Wb, 4096);
    hipLaunchKernelGGL((gemm_bb<false>), gg, bb, 0, stream, INb, Wb, (void*)Vb, M, N, K);
    hipLaunchKernelGGL(cvt_prep, dim3(512), bb, 0, stream,
                       (const float*)nullptr, (unsigned short*)nullptr, Wo, Wb, 0);
    if (useMadd) {
      hipLaunchKernelGGL(mask_madd, dim3(16384), bb, 0, stream, msk, madd, snb);
      hipLaunchKernelGGL((attn_sn<2>), ga, bb, 0, stream,
                         Qb, Kb, Vb, msk, (const unsigned int*)nullptr, madd, snb, Ob);
    } else {
      hipLaunchKernelGGL(pack_mask, dim3(65536), bb, 0, stream,
                         msk, (unsigned long long*)bits);
      hipLaunchKernelGGL((attn_sn<1>), ga, bb, 0, stream,
                         Qb, Kb, Vb, msk, bits, (const float*)nullptr, snb, Ob);
    }
    hipLaunchKernelGGL((gemm_bb<true>), gg, bb, 0, stream, Ob, Wb, (void*)out, M, N, K);
  } else {
    // --- fallback: round-5 known-good path (needs only 50.3 MB ws)
    unsigned short *Qb, *Kb, *Vb, *Ob;
    if (ws_size >= 4 * TOK * sizeof(unsigned short)) {
      Qb = (unsigned short*)d_ws;
      Kb = Qb + TOK;
      Vb = Qb + 2 * TOK;
      Ob = Qb + 3 * TOK;
    } else {
      Qb = (unsigned short*)d_out;
      Kb = (unsigned short*)d_ws;
      Vb = Kb + TOK;
      Ob = Kb + 2 * TOK;
    }
    hipLaunchKernelGGL((gemm_bt<false, false>), gg, bb, 0, stream, (const void*)iQ, Wq, (void*)Qb, M, N, K);
    hipLaunchKernelGGL((gemm_bt<false, false>), gg, bb, 0, stream, (const void*)iK, Wk, (void*)Kb, M, N, K);
    hipLaunchKernelGGL((gemm_bt<false, false>), gg, bb, 0, stream, (const void*)iV, Wv, (void*)Vb, M, N, K);
    hipLaunchKernelGGL((attn_sn<0>), ga, bb, 0, stream,
                       Qb, Kb, Vb, msk, (const unsigned int*)nullptr,
                       (const float*)nullptr, snb, Ob);
    hipLaunchKernelGGL((gemm_bt<true, true>), gg, bb, 0, stream, (const void*)Ob, Wo, (void*)out, M, N, K);
  }
}

// Round 2
// 441.805 us; speedup vs baseline: 2.6139x; 2.6139x over previous
//
#include <hip/hip_runtime.h>
#include <stdint.h>

// Problem constants
#define B_   4
#define NQ_  2048
#define SK_  2048
#define H_   16
#define HS_  1024   // HSIZE = OSIZE = ISIZE
#define D_   64
#define TOKc ((size_t)B_ * NQ_ * HS_)   // 8388608
#define WEc  ((size_t)HS_ * HS_)        // 1048576

typedef __attribute__((ext_vector_type(8))) short bf16x8;          // MFMA A/B frag (4 VGPR)
typedef __attribute__((ext_vector_type(4))) float f32x4;           // MFMA C/D frag
typedef __attribute__((ext_vector_type(2))) float f32x2;           // packed-f32 pair
typedef __attribute__((ext_vector_type(8))) unsigned short u16x8;  // 8 bf16 = 16B
typedef __attribute__((ext_vector_type(4))) int i32x4;             // 4 int32 = 16B

#define DEVI __device__ __forceinline__

// fp32 -> bf16, round-half-up (1 v_add)
DEVI unsigned short f2bf_hu(float f) {
  union { float f; unsigned int i; } x; x.f = f;
  return (unsigned short)((x.i + 0x8000u) >> 16);
}
// two fp32 -> packed bf16x2: 2 v_add + 1 v_perm
DEVI unsigned int pack2(float a, float b) {
  union { float f; unsigned int i; } x, y; x.f = a; y.f = b;
  return __builtin_amdgcn_perm(y.i + 0x8000u, x.i + 0x8000u, 0x07060302u);
}
DEVI u16x8 cvt8(f32x4 lo, f32x4 hi) {  // 8 fp32 -> 8 bf16
  union { u16x8 s; unsigned int w[4]; } r;
  r.w[0] = pack2(lo[0], lo[1]);
  r.w[1] = pack2(lo[2], lo[3]);
  r.w[2] = pack2(hi[0], hi[1]);
  r.w[3] = pack2(hi[2], hi[3]);
  return r.s;
}
DEVI void async16(void* lds, const void* g) {  // 16B global->LDS DMA (dest = lane-contiguous)
  __builtin_amdgcn_global_load_lds(
      (const __attribute__((address_space(1))) unsigned int*)g,
      (__attribute__((address_space(3))) unsigned int*)lds, 16, 0, 0);
}

// ---- packed-f32 VOP3P helpers (CDNA has v_pk_{fma,mul,add}_f32) ----
DEVI f32x2 pkfma(f32x2 a, f32x2 b, f32x2 c) {
  f32x2 d;
  asm("v_pk_fma_f32 %0, %1, %2, %3" : "=v"(d) : "v"(a), "v"(b), "v"(c));
  return d;
}
DEVI f32x2 pkmul(f32x2 a, f32x2 b) {
  f32x2 d;
  asm("v_pk_mul_f32 %0, %1, %2" : "=v"(d) : "v"(a), "v"(b));
  return d;
}
DEVI f32x2 pkadd(f32x2 a, f32x2 b) {
  f32x2 d;
  asm("v_pk_add_f32 %0, %1, %2" : "=v"(d) : "v"(a), "v"(b));
  return d;
}
// 2 f32 -> 1 u32 of 2 bf16 (RNE)
DEVI unsigned int cvtpk_bf16(float lo, float hi) {
  unsigned int r;
  asm("v_cvt_pk_bf16_f32 %0, %1, %2" : "=v"(r) : "v"(lo), "v"(hi));
  return r;
}
// keep-mask: bit OFF of nb (inverted mask) == 1 -> keep x, else 0.
// v_bfe_i32 width-1 sign-extends the bit to 0 / 0xFFFFFFFF; AND with x bits.
template <int OFF>
DEVI float keepf(float x, unsigned int nb) {
  int k;
  asm("v_bfe_i32 %0, %1, %2, 1" : "=v"(k) : "v"(nb), "i"(OFF));
  union { float f; int i; } u; u.f = x; u.i &= k;
  return u.f;
}

// LDS swizzle for [R][64] bf16 tiles (128B rows): XOR 16B-slot with row&7.
// All staged reads/writes land at the free 2-way bank-aliasing minimum (m136).
#define SWZB(row, colb) ((((row) * 128) + (colb)) ^ (((row) & 7) << 4))

// ---------------------------------------------------------------------------
// Prep kernels
// ---------------------------------------------------------------------------
__global__ __launch_bounds__(256)
void cvt_prep(const float* __restrict__ a, unsigned short* __restrict__ ab,
              const float* __restrict__ wsrc, unsigned short* __restrict__ wdst,
              int naBlocks) {
  const int bi = blockIdx.x;
  const float* s; unsigned short* d; size_t base;
  if (bi < naBlocks) { s = a;    d = ab;   base = (size_t)bi * 2048; }
  else               { s = wsrc; d = wdst; base = (size_t)(bi - naBlocks) * 2048; }
  const size_t o = base + (size_t)threadIdx.x * 8;
  f32x4 lo = *(const f32x4*)(s + o);
  f32x4 hi = *(const f32x4*)(s + o + 4);
  *(u16x8*)(d + o) = cvt8(lo, hi);
}

// Fused: iQ,iK,iV -> ACT (3*TOK bf16), Wq,Wk,Wv,Wo -> WALL (4*WE bf16).
// grid = 3*4096 + 4*512 = 14336 blocks.
__global__ __launch_bounds__(256)
void cvt_all(const float* __restrict__ iQ, const float* __restrict__ iK,
             const float* __restrict__ iV, const float* __restrict__ Wq,
             const float* __restrict__ Wk, const float* __restrict__ Wv,
             const float* __restrict__ Wo, unsigned short* __restrict__ ACT,
             unsigned short* __restrict__ WALL) {
  const int bi = blockIdx.x;
  const float* s; unsigned short* d; size_t base;
  if (bi < 12288) {
    const int which = bi >> 12;  // /4096
    s = (which == 0) ? iQ : (which == 1) ? iK : iV;
    d = ACT + (size_t)which * TOKc;
    base = (size_t)(bi & 4095) * 2048;
  } else {
    const int wi = (bi - 12288) >> 9;  // /512
    s = (wi == 0) ? Wq : (wi == 1) ? Wk : (wi == 2) ? Wv : Wo;
    d = WALL + (size_t)wi * WEc;
    base = (size_t)((bi - 12288) & 511) * 2048;
  }
  const size_t o = base + (size_t)threadIdx.x * 8;
  f32x4 lo = *(const f32x4*)(s + o);
  f32x4 hi = *(const f32x4*)(s + o + 4);
  *(u16x8*)(d + o) = cvt8(lo, hi);
}

// mask int32 -> bitmask (bit i of word w = mask[w*64+i]); 67 MB -> 2 MB
__global__ __launch_bounds__(256)
void pack_mask(const int* __restrict__ m, unsigned long long* __restrict__ bits) {
  const size_t tid = (size_t)blockIdx.x * 256 + threadIdx.x;
  const unsigned long long bal = __ballot(m[tid] != 0);
  if ((threadIdx.x & 63) == 0) bits[tid >> 6] = bal;
}

// ---------------------------------------------------------------------------
// FAST GEMM body: C[M][N] = A[M][K] @ W[N][K]^T, bf16 in via global_load_lds.
// 128x128 tile, BK=32, 4 waves. XOR swizzle applied on the GLOBAL side so the
// LDS dest stays lane-contiguous for the DMA while frag ds_read_b128 lands
// 2-way per bank (free, m136).
// ---------------------------------------------------------------------------
template <bool CF32>
DEVI void gemm_body(const unsigned short* __restrict__ A,
                    const unsigned short* __restrict__ Wb,
                    void* __restrict__ Cp, int M, int N, int K,
                    unsigned short* As, unsigned short* Bs) {
  const int t = threadIdx.x;
  const int w = t >> 6, l = t & 63;
  const int lm = l & 15, lg = l >> 4;
  const int bm = blockIdx.x * 128, bn = blockIdx.y * 128;
  const int wm = (w >> 1) * 64, wn = (w & 1) * 64;

  const int sr = t >> 2;                            // staged row 0..63 (and +64)
  const int sg = ((t & 3) ^ ((t >> 3) & 3)) * 8;    // swizzled global col-group
  const unsigned short* Ag0 = A + (size_t)(bm + sr) * K + sg;
  const unsigned short* Ag1 = A + (size_t)(bm + sr + 64) * K + sg;
  const unsigned short* Wg0 = Wb + (size_t)(bn + sr) * K + sg;
  const unsigned short* Wg1 = Wb + (size_t)(bn + sr + 64) * K + sg;
  unsigned short* lA0 = &As[t * 8];
  unsigned short* lA1 = &As[t * 8 + 2048];
  unsigned short* lB0 = &Bs[t * 8];
  unsigned short* lB1 = &Bs[t * 8 + 2048];

  const int fx = (lm >> 1) & 3;  // frag-read swizzle: (row>>1)&3 == (lm>>1)&3
  f32x4 acc[4][4] = {};

  for (int k0 = 0; k0 < K; k0 += 32) {
    async16(lA0, Ag0 + k0);
    async16(lA1, Ag1 + k0);
    async16(lB0, Wg0 + k0);
    async16(lB1, Wg1 + k0);
    __syncthreads();
    bf16x8 aF[4], bF[4];
#pragma unroll
    for (int i = 0; i < 4; i++)
      aF[i] = *(const bf16x8*)&As[(wm + i * 16 + lm) * 32 + ((lg ^ fx) * 8)];
#pragma unroll
    for (int i = 0; i < 4; i++)
      bF[i] = *(const bf16x8*)&Bs[(wn + i * 16 + lm) * 32 + ((lg ^ fx) * 8)];
    __builtin_amdgcn_s_setprio(1);
#pragma unroll
    for (int i = 0; i < 4; i++)
#pragma unroll
      for (int j = 0; j < 4; j++)
        acc[i][j] = __builtin_amdgcn_mfma_f32_16x16x32_bf16(aF[i], bF[j], acc[i][j], 0, 0, 0);
    __builtin_amdgcn_s_setprio(0);
    __syncthreads();
  }
#pragma unroll
  for (int i = 0; i < 4; i++)
#pragma unroll
    for (int j = 0; j < 4; j++) {
      const int row = bm + wm + i * 16 + lg * 4;
      const int col = bn + wn + j * 16 + lm;
#pragma unroll
      for (int r = 0; r < 4; r++) {
        if constexpr (CF32) {
          ((float*)Cp)[(size_t)(row + r) * N + col] = acc[i][j][r];
        } else {
          ((unsigned short*)Cp)[(size_t)(row + r) * N + col] = f2bf_hu(acc[i][j][r]);
        }
      }
    }
}

template <bool CF32>
__global__ __launch_bounds__(256)
void gemm_bb(const unsigned short* __restrict__ A, const unsigned short* __restrict__ Wb,
             void* __restrict__ Cp, int M, int N, int K) {
  __shared__ unsigned short As[128 * 32];
  __shared__ unsigned short Bs[128 * 32];
  gemm_body<CF32>(A, Wb, Cp, M, N, K, As, Bs);
}

// Fused Q/K/V projection: grid (M/128, N/128, 3); z selects tensor.
// 1536 blocks = 6 blocks/CU (vs 2/CU for a single 512-block GEMM).
__global__ __launch_bounds__(256)
void gemm_qkv(const unsigned short* __restrict__ ACT, const unsigned short* __restrict__ WALL,
              unsigned short* __restrict__ Qb, unsigned short* __restrict__ Kb,
              unsigned short* __restrict__ Vb, int M, int N, int K) {
  __shared__ unsigned short As[128 * 32];
  __shared__ unsigned short Bs[128 * 32];
  const int z = blockIdx.z;
  const unsigned short* A = ACT + (size_t)z * (size_t)M * (size_t)K;
  const unsigned short* W = WALL + (size_t)z * (size_t)N * (size_t)K;
  unsigned short* C = (z == 0) ? Qb : ((z == 1) ? Kb : Vb);
  gemm_body<false>(A, W, (void*)C, M, N, K, As, Bs);
}

// ---------------------------------------------------------------------------
// FALLBACK GEMM (round-5): fp32 inputs, cvt-on-stage, register prefetch.
// ---------------------------------------------------------------------------
template <bool ABF16, bool CF32>
__global__ __launch_bounds__(256)
void gemm_bt(const void* __restrict__ Ap, const float* __restrict__ W,
             void* __restrict__ Cp, int M, int N, int K) {
  __shared__ unsigned short As[128 * 40];
  __shared__ unsigned short Bs[128 * 40];
  const int t = threadIdx.x;
  const int w = t >> 6, l = t & 63;
  const int lm = l & 15, lg = l >> 4;
  const int bm = blockIdx.x * 128, bn = blockIdx.y * 128;
  const int wm = (w >> 1) * 64, wn = (w & 1) * 64;
  const int sr = t >> 2, sc = (t & 3) * 8;
  const float* Af = (const float*)Ap;
  const unsigned short* Ab = (const unsigned short*)Ap;
  const size_t ao0 = (size_t)(bm + sr) * K + sc;
  const size_t ao1 = (size_t)(bm + sr + 64) * K + sc;
  const size_t wo0 = (size_t)(bn + sr) * K + sc;
  const size_t wo1 = (size_t)(bn + sr + 64) * K + sc;
  auto loadA = [&](size_t off) -> u16x8 {
    if constexpr (ABF16) {
      return *(const u16x8*)(Ab + off);
    } else {
      f32x4 lo = *(const f32x4*)(Af + off);
      f32x4 hi = *(const f32x4*)(Af + off + 4);
      return cvt8(lo, hi);
    }
  };
  auto loadW = [&](size_t off) -> u16x8 {
    f32x4 lo = *(const f32x4*)(W + off);
    f32x4 hi = *(const f32x4*)(W + off + 4);
    return cvt8(lo, hi);
  };
  u16x8 pa0 = loadA(ao0), pa1 = loadA(ao1);
  u16x8 pb0 = loadW(wo0), pb1 = loadW(wo1);
  f32x4 acc[4][4] = {};
  for (int k0 = 0; k0 < K; k0 += 32) {
    *(u16x8*)&As[sr * 40 + sc]        = pa0;
    *(u16x8*)&As[(sr + 64) * 40 + sc] = pa1;
    *(u16x8*)&Bs[sr * 40 + sc]        = pb0;
    *(u16x8*)&Bs[(sr + 64) * 40 + sc] = pb1;
    __syncthreads();
    if (k0 + 32 < K) {
      pa0 = loadA(ao0 + k0 + 32);
      pa1 = loadA(ao1 + k0 + 32);
      pb0 = loadW(wo0 + k0 + 32);
      pb1 = loadW(wo1 + k0 + 32);
    }
    bf16x8 aF[4], bF[4];
#pragma unroll
    for (int i = 0; i < 4; i++)
      aF[i] = *(const bf16x8*)&As[(wm + i * 16 + lm) * 40 + lg * 8];
#pragma unroll
    for (int i = 0; i < 4; i++)
      bF[i] = *(const bf16x8*)&Bs[(wn + i * 16 + lm) * 40 + lg * 8];
#pragma unroll
    for (int i = 0; i < 4; i++)
#pragma unroll
      for (int j = 0; j < 4; j++)
        acc[i][j] = __builtin_amdgcn_mfma_f32_16x16x32_bf16(aF[i], bF[j], acc[i][j], 0, 0, 0);
    __syncthreads();
  }
#pragma unroll
  for (int i = 0; i < 4; i++)
#pragma unroll
    for (int j = 0; j < 4; j++) {
      const int row = bm + wm + i * 16 + lg * 4;
      const int col = bn + wn + j * 16 + lm;
#pragma unroll
      for (int r = 0; r < 4; r++) {
        if constexpr (CF32) {
          ((float*)Cp)[(size_t)(row + r) * N + col] = acc[i][j][r];
        } else {
          ((unsigned short*)Cp)[(size_t)(row + r) * N + col] = f2bf_hu(acc[i][j][r]);
        }
      }
    }
}

// ---------------------------------------------------------------------------
// SparseNormer attention, one (b, h, 128-q tile) per block, 256 threads.
// MODE 0: int32 mask (fallback)  MODE 1: 2 MB bitmask (packed-VALU softmax).
// All LDS tiles stride-64 with XOR swizzle (SWZB).
// NOTE: plain __launch_bounds__(256) — round-1's (256,4) capped VGPR at 64 and
// spilled ~1.3 GB/dispatch to scratch.
// ---------------------------------------------------------------------------
template <int MODE>
__global__ __launch_bounds__(256)
void attn_sn(const unsigned short* __restrict__ Qb,
             const unsigned short* __restrict__ Kb,
             const unsigned short* __restrict__ Vb,
             const int* __restrict__ mask,
             const unsigned int* __restrict__ bits,
             const float* __restrict__ snb,
             unsigned short* __restrict__ Ob) {
  __shared__ unsigned short Ks[64 * 64];   // [k][d]        8 KB
  __shared__ unsigned short Vt[64 * 64];   // [d][k]        8 KB
  __shared__ unsigned short Pq[128 * 64];  // [q][k]/[q][d] 16 KB
  // denom buffer overlaid on Ks after the k-loop (Ks dead by then)

  const int h = blockIdx.x, qt = blockIdx.y, b = blockIdx.z;
  const int t = threadIdx.x, w = t >> 6, l = t & 63;
  const int lm = l & 15, lg = l >> 4;
  const int q0 = qt * 128;
  const int wk = (w >> 1) * 32;
  const int wn = (w & 1) * 64;
  const float bias = snb[0];

  char* KsB = (char*)Ks;
  char* VtB = (char*)Vt;
  char* PqB = (char*)Pq;

  bf16x8 bQ[4][2];
#pragma unroll
  for (int ni = 0; ni < 4; ni++)
#pragma unroll
    for (int kf = 0; kf < 2; kf++) {
      const int qq = q0 + wn + ni * 16 + lm;
      bQ[ni][kf] = *(const bf16x8*)&Qb[(size_t)(b * NQ_ + qq) * HS_ + h * D_ + kf * 32 + lg * 8];
    }

  const int kr = t >> 3, kcb = (t & 7) * 16;  // staged K row / col-bytes
  const unsigned short* Kg = Kb + (size_t)(b * SK_) * HS_ + h * D_ + (t & 7) * 8;
  const int va = t & 31;
  const int vc = (t >> 5) * 8;
  const unsigned short* Vg = Vb + (size_t)(b * SK_) * HS_ + h * D_ + vc;
  const int* mbase = mask + (size_t)b * NQ_ * SK_;

  f32x4 oacc[2][4] = {};
  float dpart[4] = {0.f, 0.f, 0.f, 0.f};
  f32x2 dp2[4] = {};

  u16x8 pk0 = *(const u16x8*)(Kg + (size_t)(kr) * HS_);
  u16x8 pk1 = *(const u16x8*)(Kg + (size_t)(32 + kr) * HS_);
  u16x8 pv0 = *(const u16x8*)(Vg + (size_t)(2 * va) * HS_);
  u16x8 pv1 = *(const u16x8*)(Vg + (size_t)(2 * va + 1) * HS_);

  for (int kt = 0; kt < SK_ / 64; kt++) {
    const int kk0 = kt * 64;
    *(u16x8*)(KsB + SWZB(kr, kcb))      = pk0;
    *(u16x8*)(KsB + SWZB(kr + 32, kcb)) = pk1;
    {
      union { u16x8 s; unsigned int w4[4]; } a0, a1;
      a0.s = pv0; a1.s = pv1;
#pragma unroll
      for (int ww = 0; ww < 4; ww++) {
        unsigned int lo = __builtin_amdgcn_perm(a1.w4[ww], a0.w4[ww], 0x05040100u);
        unsigned int hi = __builtin_amdgcn_perm(a1.w4[ww], a0.w4[ww], 0x07060302u);
        *(unsigned int*)(VtB + SWZB(vc + 2 * ww,     4 * va)) = lo;
        *(unsigned int*)(VtB + SWZB(vc + 2 * ww + 1, 4 * va)) = hi;
      }
    }
    __syncthreads();

    if (kt + 1 < SK_ / 64) {
      const int nk0 = kk0 + 64;
      pk0 = *(const u16x8*)(Kg + (size_t)(nk0 + kr) * HS_);
      pk1 = *(const u16x8*)(Kg + (size_t)(nk0 + 32 + kr) * HS_);
      pv0 = *(const u16x8*)(Vg + (size_t)(nk0 + 2 * va) * HS_);
      pv1 = *(const u16x8*)(Vg + (size_t)(nk0 + 2 * va + 1) * HS_);
    }

    // --- mask preload (hidden under QK^T MFMAs)
    i32x4 mq[4][2];
    unsigned int mb[4];
    if constexpr (MODE == 1) {
#pragma unroll
      for (int ni = 0; ni < 4; ni++)
        mb[ni] = bits[(size_t)(b * NQ_ + q0 + wn + ni * 16 + lm) * 64 + kt * 2 + (wk >> 5)];
    } else {
#pragma unroll
      for (int ni = 0; ni < 4; ni++) {
        const int* mrow = mbase + (size_t)(q0 + wn + ni * 16 + lm) * SK_ + kk0 + wk + lg * 4;
#pragma unroll
        for (int mi = 0; mi < 2; mi++) mq[ni][mi] = *(const i32x4*)(mrow + mi * 16);
      }
    }

    // --- S^T = K . Q^T
    bf16x8 aK[2][2];
#pragma unroll
    for (int mi = 0; mi < 2; mi++)
#pragma unroll
      for (int kf = 0; kf < 2; kf++)
        aK[mi][kf] = *(const bf16x8*)(KsB + SWZB(wk + mi * 16 + lm, kf * 64 + lg * 16));
    f32x4 sf[2][4] = {};
    __builtin_amdgcn_s_setprio(1);
#pragma unroll
    for (int mi = 0; mi < 2; mi++)
#pragma unroll
      for (int ni = 0; ni < 4; ni++) {
        sf[mi][ni] = __builtin_amdgcn_mfma_f32_16x16x32_bf16(aK[mi][0], bQ[ni][0], sf[mi][ni], 0, 0, 0);
        sf[mi][ni] = __builtin_amdgcn_mfma_f32_16x16x32_bf16(aK[mi][1], bQ[ni][1], sf[mi][ni], 0, 0, 0);
      }
    __builtin_amdgcn_s_setprio(0);

    // --- mask + relu^2, denom, pack P
    if constexpr (MODE == 1) {
      const f32x2 c8 = {0.125f, 0.125f};
      const f32x2 bias2 = {bias, bias};
#pragma unroll
      for (int ni = 0; ni < 4; ni++) {
        // inverted mask, pre-shifted so bit position = mi*16 + r (const)
        const unsigned int nb = (~mb[ni]) >> (lg * 4);
#pragma unroll
        for (int mi = 0; mi < 2; mi++) {
          const f32x4 sv = sf[mi][ni];
          f32x2 t01 = pkfma((f32x2){sv[0], sv[1]}, c8, bias2);
          f32x2 t23 = pkfma((f32x2){sv[2], sv[3]}, c8, bias2);
          float x0 = fmaxf(t01[0], 0.f), x1 = fmaxf(t01[1], 0.f);
          float x2 = fmaxf(t23[0], 0.f), x3 = fmaxf(t23[1], 0.f);
          if (mi == 0) {
            x0 = keepf<0>(x0, nb);  x1 = keepf<1>(x1, nb);
            x2 = keepf<2>(x2, nb);  x3 = keepf<3>(x3, nb);
          } else {
            x0 = keepf<16>(x0, nb); x1 = keepf<17>(x1, nb);
            x2 = keepf<18>(x2, nb); x3 = keepf<19>(x3, nb);
          }
          const f32x2 u01 = pkmul((f32x2){x0, x1}, (f32x2){x0, x1});
          const f32x2 u23 = pkmul((f32x2){x2, x3}, (f32x2){x2, x3});
          dp2[ni] = pkadd(dp2[ni], u01);
          dp2[ni] = pkadd(dp2[ni], u23);
          const unsigned long long pk =
              (unsigned long long)cvtpk_bf16(u01[0], u01[1]) |
              ((unsigned long long)cvtpk_bf16(u23[0], u23[1]) << 32);
          *(unsigned long long*)(PqB + SWZB(wn + ni * 16 + lm, (wk + mi * 16 + lg * 4) * 2)) = pk;
        }
      }
    } else {
#pragma unroll
      for (int ni = 0; ni < 4; ni++) {
        float dsum = 0.f;
#pragma unroll
        for (int mi = 0; mi < 2; mi++) {
          const f32x4 sv = sf[mi][ni];
          float x2[4];
#pragma unroll
          for (int r = 0; r < 4; r++) {
            float x = fmaxf(sv[r] * 0.125f + bias, 0.f);
            x = mq[ni][mi][r] ? 0.f : x;
            x2[r] = x * x;
            dsum += x2[r];
          }
          const unsigned long long pk =
              (unsigned long long)pack2(x2[0], x2[1]) |
              ((unsigned long long)pack2(x2[2], x2[3]) << 32);
          *(unsigned long long*)(PqB + SWZB(wn + ni * 16 + lm, (wk + mi * 16 + lg * 4) * 2)) = pk;
        }
        dpart[ni] += dsum;
      }
    }
    __syncthreads();

    // --- O^T += V^T . P^T
#pragma unroll
    for (int k2 = 0; k2 < 2; k2++) {
      bf16x8 aV[2], bP[4];
#pragma unroll
      for (int mi = 0; mi < 2; mi++)
        aV[mi] = *(const bf16x8*)(VtB + SWZB(wk + mi * 16 + lm, k2 * 64 + lg * 16));
#pragma unroll
      for (int ni = 0; ni < 4; ni++)
        bP[ni] = *(const bf16x8*)(PqB + SWZB(wn + ni * 16 + lm, k2 * 64 + lg * 16));
      __builtin_amdgcn_s_setprio(1);
#pragma unroll
      for (int mi = 0; mi < 2; mi++)
#pragma unroll
        for (int ni = 0; ni < 4; ni++)
          oacc[mi][ni] = __builtin_amdgcn_mfma_f32_16x16x32_bf16(aV[mi], bP[ni], oacc[mi][ni], 0, 0, 0);
      __builtin_amdgcn_s_setprio(0);
    }
    __syncthreads();
  }

  float* denomS = (float*)Ks;  // Ks dead; loop-final barrier ordered all reads
#pragma unroll
  for (int ni = 0; ni < 4; ni++) {
    float v = (MODE == 1) ? (dp2[ni][0] + dp2[ni][1]) : dpart[ni];
    v += __shfl_xor(v, 16, 64);
    v += __shfl_xor(v, 32, 64);
    dpart[ni] = v;
  }
  if (((w >> 1) == 0) && (lg == 0)) {
#pragma unroll
    for (int ni = 0; ni < 4; ni++) denomS[wn + ni * 16 + lm] = dpart[ni];
  }
  __syncthreads();
  if (((w >> 1) == 1) && (lg == 0)) {
#pragma unroll
    for (int ni = 0; ni < 4; ni++) denomS[wn + ni * 16 + lm] += dpart[ni];
  }
  __syncthreads();

#pragma unroll
  for (int ni = 0; ni < 4; ni++) {
    const int ql = wn + ni * 16 + lm;
    const float inv = 1.0f / (denomS[ql] + 1e-32f);
#pragma unroll
    for (int mi = 0; mi < 2; mi++) {
      const int d0 = wk + mi * 16 + lg * 4;
      const f32x4 ov = oacc[mi][ni];
      const unsigned long long pk =
          (unsigned long long)cvtpk_bf16(ov[0] * inv, ov[1] * inv) |
          ((unsigned long long)cvtpk_bf16(ov[2] * inv, ov[3] * inv) << 32);
      *(unsigned long long*)(PqB + SWZB(ql, d0 * 2)) = pk;
    }
  }
  __syncthreads();
  const int qf = t >> 1;
  unsigned short* orow = Ob + (size_t)(b * NQ_ + q0 + qf) * HS_ + h * D_ + (t & 1) * 32;
#pragma unroll
  for (int j = 0; j < 4; j++) {
    u16x8 vv = *(const u16x8*)(PqB + SWZB(qf, (t & 1) * 64 + j * 16));
    *(u16x8*)(orow + j * 8) = vv;
  }
}

// ---------------------------------------------------------------------------
extern "C" void kernel_launch(void* const* d_in, const int* in_sizes, int n_in,
                              void* d_out, int out_size, void* d_ws, size_t ws_size,
                              hipStream_t stream) {
  (void)in_sizes; (void)n_in; (void)out_size;
  const float* iQ  = (const float*)d_in[0];
  const float* iK  = (const float*)d_in[1];
  const float* iV  = (const float*)d_in[2];
  const int*   msk = (const int*)d_in[3];
  const float* Wq  = (const float*)d_in[4];
  const float* Wk  = (const float*)d_in[5];
  const float* Wv  = (const float*)d_in[6];
  const float* Wo  = (const float*)d_in[7];
  const float* snb = (const float*)d_in[8];
  float* out = (float*)d_out;

  const size_t TOK = TOKc;                             // 8.39M elems
  const size_t WE  = WEc;                              // 1.05M elems
  const size_t BITS_B = (size_t)B_ * NQ_ * SK_ / 8;    // 2.10 MB
  const size_t NEED1 = (3 * TOK + WE) * 2 + BITS_B;    // 54.5 MB
  const size_t NEEDF = (6 * TOK + 4 * WE) * 2 + BITS_B;// 111.1 MB

  const dim3 gg(64, 8, 1), bb(256, 1, 1);
  const dim3 g3(64, 8, 3);
  const dim3 ga(H_, NQ_ / 128, B_);
  const int M = B_ * NQ_, N = HS_, K = HS_;

  if (ws_size >= NEEDF) {
    // --- fused fast path: one cvt, one 3-way QKV GEMM, bitmask attn, O GEMM
    unsigned short* ACT  = (unsigned short*)d_ws;  // 3*TOK bf16 (iQ,iK,iV)
    unsigned short* WALL = ACT + 3 * TOK;          // 4*WE bf16 (Wq,Wk,Wv,Wo)
    unsigned short* Kb   = WALL + 4 * WE;
    unsigned short* Vb   = Kb + TOK;
    unsigned short* Ob   = Vb + TOK;
    unsigned int*  bits  = (unsigned int*)(Ob + TOK);
    unsigned short* Qb   = (unsigned short*)d_out;  // dead before final GEMM
    unsigned short* Wob  = WALL + 3 * WE;

    hipLaunchKernelGGL(cvt_all, dim3(14336), bb, 0, stream,
                       iQ, iK, iV, Wq, Wk, Wv, Wo, ACT, WALL);
    hipLaunchKernelGGL(gemm_qkv, g3, bb, 0, stream, ACT, WALL, Qb, Kb, Vb, M, N, K);
    hipLaunchKernelGGL(pack_mask, dim3(65536), bb, 0, stream,
                       msk, (unsigned long long*)bits);
    hipLaunchKernelGGL((attn_sn<1>), ga, bb, 0, stream,
                       Qb, Kb, Vb, msk, bits, snb, Ob);
    hipLaunchKernelGGL((gemm_bb<true>), gg, bb, 0, stream, Ob, Wob, (void*)out, M, N, K);
  } else if (ws_size >= NEED1) {
    // --- round-0 path: per-tensor cvt + GEMM, bitmask attn
    unsigned short* Kb = (unsigned short*)d_ws;
    unsigned short* Vb = Kb + TOK;
    unsigned short* Ob = Vb + TOK;
    unsigned short* Wb = Ob + TOK;
    unsigned int* bits = (unsigned int*)(Wb + WE);
    unsigned short* out_us = (unsigned short*)d_out;
    unsigned short* Qb  = out_us;         // d_out lower half (dead before final GEMM)
    unsigned short* INb = out_us + TOK;   // d_out upper half: staging for bf16 A

    hipLaunchKernelGGL(cvt_prep, dim3(4608), bb, 0, stream, iQ, INb, Wq, Wb, 4096);
    hipLaunchKernelGGL((gemm_bb<false>), gg, bb, 0, stream, INb, Wb, (void*)Qb, M, N, K);
    hipLaunchKernelGGL(cvt_prep, dim3(4608), bb, 0, stream, iK, INb, Wk, Wb, 4096);
    hipLaunchKernelGGL((gemm_bb<false>), gg, bb, 0, stream, INb, Wb, (void*)Kb, M, N, K);
    hipLaunchKernelGGL(cvt_prep, dim3(4608), bb, 0, stream, iV, INb, Wv, Wb, 4096);
    hipLaunchKernelGGL((gemm_bb<false>), gg, bb, 0, stream, INb, Wb, (void*)Vb, M, N, K);
    hipLaunchKernelGGL(cvt_prep, dim3(512), bb, 0, stream,
                       (const float*)nullptr, (unsigned short*)nullptr, Wo, Wb, 0);
    hipLaunchKernelGGL(pack_mask, dim3(65536), bb, 0, stream,
                       msk, (unsigned long long*)bits);
    hipLaunchKernelGGL((attn_sn<1>), ga, bb, 0, stream,
                       Qb, Kb, Vb, msk, bits, snb, Ob);
    hipLaunchKernelGGL((gemm_bb<true>), gg, bb, 0, stream, Ob, Wb, (void*)out, M, N, K);
  } else {
    // --- fallback: round-5 known-good path (needs only 50.3 MB ws)
    unsigned short *Qb, *Kb, *Vb, *Ob;
    if (ws_size >= 4 * TOK * sizeof(unsigned short)) {
      Qb = (unsigned short*)d_ws;
      Kb = Qb + TOK;
      Vb = Qb + 2 * TOK;
      Ob = Qb + 3 * TOK;
    } else {
      Qb = (unsigned short*)d_out;
      Kb = (unsigned short*)d_ws;
      Vb = Kb + TOK;
      Ob = Kb + 2 * TOK;
    }
    hipLaunchKernelGGL((gemm_bt<false, false>), gg, bb, 0, stream, (const void*)iQ, Wq, (void*)Qb, M, N, K);
    hipLaunchKernelGGL((gemm_bt<false, false>), gg, bb, 0, stream, (const void*)iK, Wk, (void*)Kb, M, N, K);
    hipLaunchKernelGGL((gemm_bt<false, false>), gg, bb, 0, stream, (const void*)iV, Wv, (void*)Vb, M, N, K);
    hipLaunchKernelGGL((attn_sn<0>), ga, bb, 0, stream,
                       Qb, Kb, Vb, msk, (const unsigned int*)nullptr, snb, Ob);
    hipLaunchKernelGGL((gemm_bt<true, true>), gg, bb, 0, stream, (const void*)Ob, Wo, (void*)out, M, N, K);
  }
}